// Round 7
// baseline (6594.221 us; speedup 1.0000x reference)
//
#include <hip/hip_runtime.h>
#include <math.h>

#define GEPS 1e-7f
#define BNEPS 1e-5f

typedef unsigned short u16;
typedef unsigned int   u32;

typedef _Float16 f16x8 __attribute__((ext_vector_type(8)));
typedef float    f32x4 __attribute__((ext_vector_type(4)));

__device__ __forceinline__ float h2f(u16 u){
  _Float16 x = __builtin_bit_cast(_Float16, u); return (float)x;
}
__device__ __forceinline__ u16 f2h(float f){
  _Float16 x = (_Float16)f; return __builtin_bit_cast(u16, x);
}

// ---------------------------------------------------------------- utilities
__global__ __launch_bounds__(256) void k_zero_i(int* __restrict__ p, int n){
  int i = blockIdx.x*256 + threadIdx.x;
  if (i < n) p[i] = 0;
}
__global__ __launch_bounds__(256) void k_zero_f(float* __restrict__ p, int n){
  int i = blockIdx.x*256 + threadIdx.x;
  if (i < n) p[i] = 0.f;
}

// ---------------------------------------------------------------- CSR build (multi-block scan)
__global__ __launch_bounds__(256) void k_hist(const int* __restrict__ dst, int E,
                                              int* __restrict__ cnt){
  int e = blockIdx.x*256 + threadIdx.x;
  if (e < E) atomicAdd(&cnt[dst[e]], 1);
}

__global__ __launch_bounds__(256) void k_blocksum(const int* __restrict__ cnt, int N,
                                                  int* __restrict__ part){
  __shared__ int s[256];
  int t = threadIdx.x, i = blockIdx.x*256 + t;
  s[t] = (i < N) ? cnt[i] : 0;
  __syncthreads();
  for (int off = 128; off > 0; off >>= 1){
    if (t < off) s[t] += s[t + off];
    __syncthreads();
  }
  if (t == 0) part[blockIdx.x] = s[0];
}

__global__ __launch_bounds__(1024) void k_scanpart(int* __restrict__ part, int NB){
  __shared__ int s[1024];
  int t = threadIdx.x;
  int v = (t < NB) ? part[t] : 0;
  s[t] = v;
  __syncthreads();
  for (int off = 1; off < 1024; off <<= 1){
    int u = (t >= off) ? s[t-off] : 0;
    __syncthreads();
    s[t] += u;
    __syncthreads();
  }
  if (t < NB) part[t] = s[t] - v;   // exclusive
}

__global__ __launch_bounds__(256) void k_scanapply(const int* __restrict__ cnt,
    const int* __restrict__ part, int N, int E,
    int* __restrict__ offs, int* __restrict__ cursor){
  __shared__ int s[256];
  int t = threadIdx.x, i = blockIdx.x*256 + t;
  int v = (i < N) ? cnt[i] : 0;
  s[t] = v;
  __syncthreads();
  for (int off = 1; off < 256; off <<= 1){
    int u = (t >= off) ? s[t-off] : 0;
    __syncthreads();
    s[t] += u;
    __syncthreads();
  }
  int ex = part[blockIdx.x] + s[t] - v;
  if (i < N){
    offs[i]   = ex;
    cursor[i] = ex;
    if (i == N-1) offs[N] = ex + v;
  }
}

__global__ __launch_bounds__(256) void k_scatter(const int* __restrict__ src,
    const int* __restrict__ dst, const int* __restrict__ attr, int E,
    int* __restrict__ cursor, int* __restrict__ esort){
  int e = blockIdx.x*256 + threadIdx.x;
  if (e >= E) return;
  int d = dst[e];
  int pos = atomicAdd(&cursor[d], 1);
  int a = (src[e] & 0x1ffff)
        | ((attr[3*(size_t)e]   & 15) << 17)
        | ((attr[3*(size_t)e+1] & 15) << 21)
        | ((attr[3*(size_t)e+2] & 15) << 25);
  esort[pos] = a;
}

// ---------------------------------------------------------------- weight prep: fp32 [L][K][N] -> fp16 [L][N][K]
__global__ __launch_bounds__(256) void k_wtrans(const float* __restrict__ W,
    u16* __restrict__ Wt, int K, int Nout, int total){
  int id = blockIdx.x*256 + threadIdx.x;
  if (id >= total) return;
  int k   = id % K;
  int rem = id / K;
  int n   = rem % Nout;
  int l   = rem / Nout;
  Wt[id] = f2h(W[((size_t)l*K + k)*Nout + n]);
}

// ---------------------------------------------------------------- atom encoder
__global__ __launch_bounds__(256) void k_atom(const int* __restrict__ x,
    const float* __restrict__ emb, float* __restrict__ h, int N){
  int d = threadIdx.x & 127;
  int n = (blockIdx.x << 1) + (threadIdx.x >> 7);
  if (n >= N) return;
  float s = 0.f;
  #pragma unroll
  for (int i = 0; i < 9; ++i){
    int idx = x[(size_t)n*9 + i];
    s += emb[((size_t)i*119 + idx)*128 + d];
  }
  h[(size_t)n*128 + d] = s;
}

// ---------------------------------------------------------------- fused edge pass:
// relu(bn(.)) inline from batch stats, one-pass softmax (args bounded ~8 by BN),
// software-pipelined: edge e+1's esort/h/bond rows prefetched while computing edge e.
template<bool PRE_BN>
__global__ __launch_bounds__(256)
void k_edge(const float* __restrict__ h,
    const int* __restrict__ offs, const int* __restrict__ esort,
    const float* __restrict__ bond,   // [3][6][128] for this layer
    const float* __restrict__ tptr,
    const float* __restrict__ ssum_, const float* __restrict__ ssq_,
    const float* __restrict__ g, const float* __restrict__ b,
    u16* __restrict__ hh, int N, float invN){
  __shared__ float sg[128], sv[128];
  int tid = threadIdx.x;
  if (PRE_BN){
    if (tid < 128){
      float mu  = ssum_[tid]*invN;
      float var = fmaxf(ssq_[tid]*invN - mu*mu, 0.f);
      float rs  = rsqrtf(var + BNEPS);
      float s   = g[tid]*rs;
      sg[tid] = s;
      sv[tid] = b[tid] - mu*s;
    }
    __syncthreads();
  }
  int lane = tid & 63;
  int n = (blockIdx.x << 2) + (tid >> 6);
  if (n >= N) return;
  int c0 = lane << 1;
  float tl = *tptr;
  float sg0=1.f, sv0=0.f, sg1=1.f, sv1=0.f;
  if (PRE_BN){ sg0=sg[c0]; sv0=sv[c0]; sg1=sg[c0+1]; sv1=sv[c0+1]; }

  int s0 = offs[n], s1 = offs[n+1];
  float den0 = 0.f, acc0 = 0.f, den1 = 0.f, acc1 = 0.f;
  if (s0 < s1){
    int se = esort[s0];
    int sidx = se & 0x1ffff;
    float2 hv = *(const float2*)(h + (size_t)sidx*128 + c0);
    float2 e0 = *(const float2*)(bond + ((se>>17)&15)*128 + c0);
    float2 e1 = *(const float2*)(bond + (6 + ((se>>21)&15))*128 + c0);
    float2 e2 = *(const float2*)(bond + (12 + ((se>>25)&15))*128 + c0);
    for (int e = s0; e < s1; ++e){
      float2 hvN = hv, e0N = e0, e1N = e1, e2N = e2;
      if (e + 1 < s1){                 // prefetch next edge's rows
        int seN = esort[e+1];
        int sidxN = seN & 0x1ffff;
        hvN = *(const float2*)(h + (size_t)sidxN*128 + c0);
        e0N = *(const float2*)(bond + ((seN>>17)&15)*128 + c0);
        e1N = *(const float2*)(bond + (6 + ((seN>>21)&15))*128 + c0);
        e2N = *(const float2*)(bond + (12 + ((seN>>25)&15))*128 + c0);
      }
      float x0 = hv.x, x1 = hv.y;
      if (PRE_BN){
        x0 = fmaxf(x0*sg0 + sv0, 0.f);
        x1 = fmaxf(x1*sg1 + sv1, 0.f);
      }
      float m0 = fmaxf(x0 + e0.x + e1.x + e2.x, 0.f) + GEPS;
      float m1 = fmaxf(x1 + e0.y + e1.y + e2.y, 0.f) + GEPS;
      float p0 = __expf(m0*tl);
      float p1 = __expf(m1*tl);
      den0 += p0; acc0 += p0*m0;
      den1 += p1; acc1 += p1*m1;
      hv = hvN; e0 = e0N; e1 = e1N; e2 = e2N;
    }
  }
  float2 hv = *(const float2*)(h + (size_t)n*128 + c0);
  float x0 = hv.x, x1 = hv.y;
  if (PRE_BN){
    x0 = fmaxf(x0*sg0 + sv0, 0.f);
    x1 = fmaxf(x1*sg1 + sv1, 0.f);
  }
  float r0 = x0 + acc0 / fmaxf(den0, GEPS);   // empty segment -> +0
  float r1 = x1 + acc1 / fmaxf(den1, GEPS);
  u32 pk = (u32)f2h(r0) | ((u32)f2h(r1) << 16);
  *((u32*)hh + (size_t)n*64 + lane) = pk;
}

// ---------------------------------------------------------------- MFMA fp16 GEMM, 128x128 tile,
// double-buffered LDS in FRAGMENT-LINEAR layout: each 32-K tile stored as
// [frag 0..7][lane 0..63][8 halves]; wave reads are base+lane*16B (conflict-free,
// m97 pattern), staging writes are a permutation of contiguous 16B blocks
// (conflict-free). Stats reduced via shfl_xor, no epilogue barriers.
template<bool TRANSFORM, bool OUT32>
__global__ __launch_bounds__(256)
void k_gemm(const u16* __restrict__ A, int lda,
            const u16* __restrict__ Wt,
            const float* __restrict__ bias,
            const float* __restrict__ sIn, const float* __restrict__ qIn,
            const float* __restrict__ gam, const float* __restrict__ bet,
            const float* __restrict__ resid,
            void* __restrict__ outv, int ldo,
            float* __restrict__ sOut, float* __restrict__ qOut,
            int M, int K){
  __shared__ __align__(16) _Float16 As[2][4096];   // [frag][lane][8]
  __shared__ __align__(16) _Float16 Bs[2][4096];
  __shared__ float sc[256], shv[256];

  int tid = threadIdx.x;
  if (TRANSFORM){
    float inv = 1.f / (float)M;
    for (int k = tid; k < K; k += 256){
      float mu  = sIn[k]*inv;
      float var = fmaxf(qIn[k]*inv - mu*mu, 0.f);
      float rs  = rsqrtf(var + BNEPS);
      float s   = gam[k]*rs;
      sc[k]  = s;
      shv[k] = bet[k] - mu*s;
    }
    __syncthreads();
  }

  int mBase = blockIdx.x * 128;
  int cBase = blockIdx.y * 128;
  int w    = tid >> 6;
  int lane = tid & 63;
  int wm = w & 1, wn = w >> 1;
  int quad = lane >> 4, ln = lane & 15;

  // staging: thread handles rows (tid>>2) and 64+(tid>>2), k-segment (tid&3)*8
  int srow = tid >> 2, sseg = tid & 3;
  int aw0 = (srow >> 4)*512 + sseg*128 + (srow & 15)*8;   // halves; frag-linear dest
  int aw1 = aw0 + 2048;                                   // rows 64..127 -> frags 4..7
  int gr0 = mBase + srow;      if (gr0 >= M) gr0 = M - 1;
  int gr1 = mBase + 64 + srow; if (gr1 >= M) gr1 = M - 1;
  const u16* a0p = A + (size_t)gr0*lda + sseg*8;
  const u16* a1p = A + (size_t)gr1*lda + sseg*8;
  const u16* b0p = Wt + (size_t)(cBase + srow)*K + sseg*8;
  const u16* b1p = Wt + (size_t)(cBase + 64 + srow)*K + sseg*8;

  // fragment read offsets (halves)
  int rdA = wm*2048 + lane*8;   // + i*512
  int rdB = wn*2048 + lane*8;   // + j*512

  f32x4 acc[4][4];
  #pragma unroll
  for (int i = 0; i < 4; ++i)
    #pragma unroll
    for (int j = 0; j < 4; ++j)
      acc[i][j] = (f32x4){0.f,0.f,0.f,0.f};

  uint4 pa0 = *(const uint4*)(a0p);
  uint4 pa1 = *(const uint4*)(a1p);
  uint4 pb0 = *(const uint4*)(b0p);
  uint4 pb1 = *(const uint4*)(b1p);

  auto xform = [&](uint4 ra, int kb)->uint4{
    float f0 = fmaxf(h2f((u16)(ra.x & 0xffff))*sc[kb+0] + shv[kb+0], 0.f);
    float f1 = fmaxf(h2f((u16)(ra.x >> 16)) *sc[kb+1] + shv[kb+1], 0.f);
    float f2 = fmaxf(h2f((u16)(ra.y & 0xffff))*sc[kb+2] + shv[kb+2], 0.f);
    float f3 = fmaxf(h2f((u16)(ra.y >> 16)) *sc[kb+3] + shv[kb+3], 0.f);
    float f4 = fmaxf(h2f((u16)(ra.z & 0xffff))*sc[kb+4] + shv[kb+4], 0.f);
    float f5 = fmaxf(h2f((u16)(ra.z >> 16)) *sc[kb+5] + shv[kb+5], 0.f);
    float f6 = fmaxf(h2f((u16)(ra.w & 0xffff))*sc[kb+6] + shv[kb+6], 0.f);
    float f7 = fmaxf(h2f((u16)(ra.w >> 16)) *sc[kb+7] + shv[kb+7], 0.f);
    uint4 o;
    o.x = (u32)f2h(f0) | ((u32)f2h(f1) << 16);
    o.y = (u32)f2h(f2) | ((u32)f2h(f3) << 16);
    o.z = (u32)f2h(f4) | ((u32)f2h(f5) << 16);
    o.w = (u32)f2h(f6) | ((u32)f2h(f7) << 16);
    return o;
  };

  // stage tile 0 into buffer 0
  {
    uint4 wa0 = TRANSFORM ? xform(pa0, sseg*8) : pa0;
    uint4 wa1 = TRANSFORM ? xform(pa1, sseg*8) : pa1;
    *(uint4*)(&As[0][aw0]) = wa0;
    *(uint4*)(&As[0][aw1]) = wa1;
    *(uint4*)(&Bs[0][aw0]) = pb0;
    *(uint4*)(&Bs[0][aw1]) = pb1;
  }

  int kTiles = K >> 5;
  for (int kt = 0; kt < kTiles; ++kt){
    __syncthreads();
    int cb = kt & 1, nb = cb ^ 1;
    int k1 = (kt + 1) << 5;
    if (kt + 1 < kTiles){               // issue next tile's global loads early
      pa0 = *(const uint4*)(a0p + k1);
      pa1 = *(const uint4*)(a1p + k1);
      pb0 = *(const uint4*)(b0p + k1);
      pb1 = *(const uint4*)(b1p + k1);
    }
    f16x8 af[4], bf[4];
    #pragma unroll
    for (int i = 0; i < 4; ++i)
      af[i] = *(const f16x8*)(&As[cb][rdA + i*512]);
    #pragma unroll
    for (int j = 0; j < 4; ++j)
      bf[j] = *(const f16x8*)(&Bs[cb][rdB + j*512]);
    #pragma unroll
    for (int i = 0; i < 4; ++i)
      #pragma unroll
      for (int j = 0; j < 4; ++j)
        acc[i][j] = __builtin_amdgcn_mfma_f32_16x16x32_f16(af[i], bf[j], acc[i][j], 0, 0, 0);
    if (kt + 1 < kTiles){               // stage next tile into alternate buffer
      uint4 wa0 = TRANSFORM ? xform(pa0, k1 + sseg*8) : pa0;
      uint4 wa1 = TRANSFORM ? xform(pa1, k1 + sseg*8) : pa1;
      *(uint4*)(&As[nb][aw0]) = wa0;
      *(uint4*)(&As[nb][aw1]) = wa1;
      *(uint4*)(&Bs[nb][aw0]) = pb0;
      *(uint4*)(&Bs[nb][aw1]) = pb1;
    }
  }

  float bv[4];
  #pragma unroll
  for (int j = 0; j < 4; ++j) bv[j] = bias[cBase + 64*wn + 16*j + ln];
  float ps[4] = {0,0,0,0}, pq[4] = {0,0,0,0};

  #pragma unroll
  for (int i = 0; i < 4; ++i){
    int rbase = mBase + 64*wm + 16*i + quad*4;
    #pragma unroll
    for (int r = 0; r < 4; ++r){
      int row = rbase + r;
      if (row < M){
        #pragma unroll
        for (int j = 0; j < 4; ++j){
          int col = cBase + 64*wn + 16*j + ln;
          size_t off = (size_t)row*ldo + col;
          float v = acc[i][j][r] + bv[j];
          if (OUT32){
            float* out = (float*)outv;
            if (resid) v += resid[off];
            out[off] = v;
            ps[j] += v; pq[j] += v*v;
          } else {
            u16* out = (u16*)outv;
            u16 q = f2h(v);
            out[off] = q;
            float vr = h2f(q);
            ps[j] += vr; pq[j] += vr*vr;
          }
        }
      }
    }
  }
  // column stats: reduce across the 4 quads (rows) of this wave via shfl_xor,
  // then one global atomic per column per wave. No barriers.
  #pragma unroll
  for (int j = 0; j < 4; ++j){
    float s = ps[j], q = pq[j];
    s += __shfl_xor(s, 16, 64);  q += __shfl_xor(q, 16, 64);
    s += __shfl_xor(s, 32, 64);  q += __shfl_xor(q, 32, 64);
    if (quad == 0){
      int cl = cBase + 64*wn + 16*j + ln;
      atomicAdd(&sOut[cl], s);
      atomicAdd(&qOut[cl], q);
    }
  }
}

// ---------------------------------------------------------------- pooling
__global__ __launch_bounds__(256) void k_pool(const float* __restrict__ h,
    const float* __restrict__ ssum, const float* __restrict__ ssq,
    const float* __restrict__ g, const float* __restrict__ b,
    const float* __restrict__ predW, const int* __restrict__ batch,
    float* __restrict__ pool, float* __restrict__ cnt, int N){
  int lane = threadIdx.x & 63;
  int n = (blockIdx.x << 2) + (threadIdx.x >> 6);
  if (n >= N) return;
  float inv = 1.f / (float)N;
  float v = 0.f;
  #pragma unroll
  for (int d = lane; d < 128; d += 64){
    float mu  = ssum[d]*inv;
    float var = fmaxf(ssq[d]*inv - mu*mu, 0.f);
    float rs  = rsqrtf(var + BNEPS);
    float bn  = (h[(size_t)n*128 + d] - mu)*(g[d]*rs) + b[d];
    v += bn * predW[d];
  }
  #pragma unroll
  for (int off = 32; off > 0; off >>= 1) v += __shfl_down(v, off, 64);
  if (lane == 0){
    int gi = batch[n];
    atomicAdd(&pool[gi], v);
    atomicAdd(&cnt[gi], 1.f);
  }
}

__global__ __launch_bounds__(256) void k_final(const float* __restrict__ pool,
    const float* __restrict__ cnt, const float* __restrict__ predb,
    float* __restrict__ out, int G){
  int g = blockIdx.x*256 + threadIdx.x;
  if (g < G) out[g] = pool[g] / fmaxf(cnt[g], 1.f) + predb[0];
}

// ---------------------------------------------------------------- launcher
extern "C" void kernel_launch(void* const* d_in, const int* in_sizes, int n_in,
                              void* d_out, int out_size, void* d_ws, size_t ws_size,
                              hipStream_t stream){
  const int*   x        = (const int*)d_in[0];
  const int*   eidx     = (const int*)d_in[1];
  const int*   eattr    = (const int*)d_in[2];
  const int*   batch    = (const int*)d_in[3];
  const float* atom_emb = (const float*)d_in[4];
  const float* bond_emb = (const float*)d_in[5];
  const float* W1 = (const float*)d_in[6];
  const float* b1 = (const float*)d_in[7];
  const float* g1 = (const float*)d_in[8];
  const float* be1= (const float*)d_in[9];
  const float* W2 = (const float*)d_in[10];
  const float* b2 = (const float*)d_in[11];
  const float* g2 = (const float*)d_in[12];
  const float* be2= (const float*)d_in[13];
  const float* W3 = (const float*)d_in[14];
  const float* b3 = (const float*)d_in[15];
  const float* tt = (const float*)d_in[16];
  const float* ng = (const float*)d_in[17];
  const float* nb = (const float*)d_in[18];
  const float* predW = (const float*)d_in[19];
  const float* predb = (const float*)d_in[20];
  float* out = (float*)d_out;

  const int N = in_sizes[3];
  const int E = in_sizes[1] / 2;
  const int L = in_sizes[16];
  const int G = out_size;
  const int D = 128, H = 256;
  const float invN = 1.f / (float)N;

  char* ws = (char*)d_ws;
  size_t off = 0;
  auto carve = [&](size_t bytes)->void*{
    void* p = ws + off;
    off += (bytes + 511) & ~(size_t)511;
    return p;
  };
  // total ~162 MB
  float* h   = (float*)carve((size_t)N*D*4);   // fp32 residual stream
  u16*   y1  = (u16*)  carve((size_t)N*H*2);   // fp16
  u16*   y2  = (u16*)  carve((size_t)N*H*2);   // fp16
  u16*   hh  = y2;   // hh (fp16, N*D) aliases y2; dead before GEMM2 writes y2
  u16*   Wt1 = (u16*) carve((size_t)L*H*D*2);  // [L][256][128]
  u16*   Wt2 = (u16*) carve((size_t)L*H*H*2);  // [L][256][256]
  u16*   Wt3 = (u16*) carve((size_t)L*D*H*2);  // [L][128][256]
  int*  offs   = (int*)carve((size_t)(N+1)*4);
  int*  cursor = (int*)carve((size_t)N*4);
  int*  cnt    = (int*)carve((size_t)N*4);
  int*  part   = (int*)carve(1024*4);
  int*  esort  = (int*)carve((size_t)E*4);
  float* stats = (float*)carve((size_t)L*1280*4);   // per-layer: s1(512) s2(512) sh(256)
  float* pool = (float*)carve((size_t)G*4);
  float* cntg = (float*)carve((size_t)G*4);

  int NB = (N + 255) / 256;

  // CSR build (once per call, shared by all 20 layers)
  k_zero_i   <<<NB, 256, 0, stream>>>(cnt, N);
  k_hist     <<<(E+255)/256, 256, 0, stream>>>(eidx + E, E, cnt);
  k_blocksum <<<NB, 256, 0, stream>>>(cnt, N, part);
  k_scanpart <<<1, 1024, 0, stream>>>(part, NB);
  k_scanapply<<<NB, 256, 0, stream>>>(cnt, part, N, E, offs, cursor);
  k_scatter  <<<(E+255)/256, 256, 0, stream>>>(eidx, eidx + E, eattr, E, cursor, esort);
  k_atom     <<<(N+1)/2, 256, 0, stream>>>(x, atom_emb, h, N);
  k_zero_f   <<<(L*1280+255)/256, 256, 0, stream>>>(stats, L*1280);

  // weights -> fp16 transposed [Nout][K]
  k_wtrans<<<((L*H*D)+255)/256, 256, 0, stream>>>(W1, Wt1, D, H, L*H*D);
  k_wtrans<<<((L*H*H)+255)/256, 256, 0, stream>>>(W2, Wt2, H, H, L*H*H);
  k_wtrans<<<((L*D*H)+255)/256, 256, 0, stream>>>(W3, Wt3, H, D, L*D*H);

  int mb = (N + 127) / 128;
  int eb = (N + 3) / 4;
  for (int l = 0; l < L; ++l){
    float* st  = stats + (size_t)l*1280;
    float* s1s = st,        *s1q = st + 256;
    float* s2s = st + 512,  *s2q = st + 768;
    float* shs = st + 1024, *shq = st + 1152;
    const float* bondl = bond_emb + (size_t)l*3*6*D;
    if (l == 0){
      k_edge<false><<<eb, 256, 0, stream>>>(h, offs, esort, bondl, tt + l,
          nullptr, nullptr, nullptr, nullptr, hh, N, invN);
    } else {
      float* stp = stats + (size_t)(l-1)*1280;
      k_edge<true><<<eb, 256, 0, stream>>>(h, offs, esort, bondl, tt + l,
          stp + 1024, stp + 1152, ng + (size_t)(l-1)*D, nb + (size_t)(l-1)*D,
          hh, N, invN);
    }
    // y1 = hh @ W1 + b1   (stats -> s1)
    k_gemm<false,false><<<dim3(mb,2), 256, 0, stream>>>(hh, D,
        Wt1 + (size_t)l*H*D, b1 + (size_t)l*H,
        nullptr, nullptr, nullptr, nullptr, nullptr,
        y1, H, s1s, s1q, N, D);
    // y2 = relu(bn(y1)) @ W2 + b2   (stats -> s2)
    k_gemm<true,false><<<dim3(mb,2), 256, 0, stream>>>(y1, H,
        Wt2 + (size_t)l*H*H, b2 + (size_t)l*H,
        s1s, s1q, g1 + (size_t)l*H, be1 + (size_t)l*H, nullptr,
        y2, H, s2s, s2q, N, H);
    // h = relu(bn(y2)) @ W3 + b3 (+ h residual for l>0)   (stats of new h -> sh)
    k_gemm<true,true><<<dim3(mb,1), 256, 0, stream>>>(y2, H,
        Wt3 + (size_t)l*D*H, b3 + (size_t)l*D,
        s2s, s2q, g2 + (size_t)l*H, be2 + (size_t)l*H,
        (l ? h : nullptr),
        h, D, shs, shq, N, H);
  }

  float* stL = stats + (size_t)(L-1)*1280;
  k_zero_f<<<(G+255)/256, 256, 0, stream>>>(pool, G);
  k_zero_f<<<(G+255)/256, 256, 0, stream>>>(cntg, G);
  k_pool  <<<(N+3)/4, 256, 0, stream>>>(h, stL + 1024, stL + 1152,
      ng + (size_t)(L-1)*D, nb + (size_t)(L-1)*D, predW, batch, pool, cntg, N);
  k_final <<<(G+255)/256, 256, 0, stream>>>(pool, cntg, predb, out, G);
}